// Round 7
// baseline (614.282 us; speedup 1.0000x reference)
//
#include <hip/hip_runtime.h>
#include <hip/hip_bf16.h>

#define EPS_BN 1e-5f

typedef __bf16 bf16_t;
typedef __bf16 bf16x8 __attribute__((ext_vector_type(8)));
typedef __bf16 bf16x4 __attribute__((ext_vector_type(4)));
typedef float fx4 __attribute__((ext_vector_type(4)));
typedef float floatx16 __attribute__((ext_vector_type(16)));

// ---------------- prep: wq + pack W fragments + packed bias ----------------
// wpack layout: (((layer*8 + cg)*16 + kt)*64 + lane)*8 + e
//   cg = col>>5 (0..7), lane = ((k>>3)&1)*32 + (col&31), e = k&7
// works as A-operand (m=col) or B-operand (n=col) fragment.
// biaspack[lay*256 + cg*32 + l2*16 + reg] = gb[cg*32 + (reg&3)+8*(reg>>2)+4*l2]
__global__ __launch_bounds__(256) void prep_kernel(
    const float* __restrict__ q, const float* __restrict__ gw1,
    const float* __restrict__ gb1, const float* __restrict__ g2,
    const float* __restrict__ g3, const float* __restrict__ g4,
    const float* __restrict__ gb2, const float* __restrict__ gb3,
    float* __restrict__ wq, bf16_t* __restrict__ wpack,
    float* __restrict__ biaspack)
{
    int blk = blockIdx.x, t = threadIdx.x;
    {
        float acc = gb1[t];
        #pragma unroll
        for (int d = 0; d < 11; d++)
            acc = fmaf(q[blk * 11 + d], gw1[(52 + d) * 256 + t], acc);
        wq[blk * 256 + t] = acc;
    }
    if (blk == 0) {
        for (int idx = t; idx < 512; idx += 256) {
            int layer = idx >> 8;
            int rem = idx & 255;
            int cg = rem >> 5, l2 = (rem >> 4) & 1, reg = rem & 15;
            int c = cg * 32 + (reg & 3) + 8 * (reg >> 2) + 4 * l2;
            biaspack[idx] = (layer ? gb3 : gb2)[c];
        }
    }
    for (int idx = blk * 3072 + t; idx < blk * 3072 + 3072; idx += 256) {
        int layer = idx >> 16;
        int rem = idx & 65535;
        int col = rem & 255;
        int k = rem >> 8;
        const float* gw = (layer == 0) ? g2 : ((layer == 1) ? g3 : g4);
        float v = gw[k * 256 + col];
        int cg = col >> 5, l31 = col & 31;
        int kt = k >> 4, l2 = (k >> 3) & 1, e = k & 7;
        int lane = l2 * 32 + l31;
        wpack[(((layer * 8 + cg) * 16 + kt) * 64 + lane) * 8 + e] = (bf16_t)v;
    }
}

// ---------------- unified conv: inline BN-finalize + fold + stats-out ------
// PSTAT = number of partial rows to reduce for input BN (0 = no fold, conv1)
template<int CIN, int HOUT, int OY_PER, int CO_PER, int PSTAT>
__global__ __launch_bounds__(256) void conv_kernel(
    const float* __restrict__ in, const float* __restrict__ part_in,
    float inv_n, const float* __restrict__ gamma,
    const float* __restrict__ beta, const float* __restrict__ w,
    const float* __restrict__ bias, float* __restrict__ out,
    float* __restrict__ part_out)
{
    const int HIN = 2 * HOUT, ROWS = 2 * OY_PER + 3, RW = 2 * HOUT + 2;
    const int TILES = HOUT / OY_PER;
    const int WPC = (HOUT * OY_PER) / 64;      // waves per channel-group
    int b = blockIdx.x / TILES, tile = blockIdx.x % TILES;
    int oy0 = tile * OY_PER;
    __shared__ float tin[CIN][ROWS][RW];
    __shared__ float scf[24], shf[24];
    __shared__ float fred[5][48];
    __shared__ float red[4][CO_PER * 2];
    int t = threadIdx.x;
    if (PSTAT > 0) {
        if (t < 240) {
            int comp = t % 48, sl = t / 48;
            float a = 0.f;
            for (int p = sl; p < PSTAT; p += 5) a += part_in[p * 48 + comp];
            fred[sl][comp] = a;
        }
        __syncthreads();
        if (t < 24) {
            float s1 = 0.f, s2 = 0.f;
            #pragma unroll
            for (int s = 0; s < 5; s++) { s1 += fred[s][2 * t]; s2 += fred[s][2 * t + 1]; }
            float m = s1 * inv_n;
            float var = s2 * inv_n - m * m;
            float sc = gamma[t] * rsqrtf(var + EPS_BN);
            scf[t] = sc;
            shf[t] = fmaf(-m, sc, beta[t]);
        }
        __syncthreads();
    }
    const int total = CIN * ROWS * RW;
    int iyb = 2 * oy0 - 1;
    #pragma unroll 2
    for (int idx = t; idx < total; idx += 256) {
        int rx = idx % RW;
        int rem = idx / RW;
        int ry = rem % ROWS;
        int ci = rem / ROWS;
        int iy = iyb + ry, ix = rx - 1;
        float v = 0.f;
        if ((unsigned)iy < (unsigned)HIN && (unsigned)ix < (unsigned)HIN) {
            float raw = in[(b * CIN + ci) * HIN * HIN + iy * HIN + ix];
            v = (PSTAT > 0) ? fmaf(raw, scf[ci], shf[ci]) : raw;
        }
        tin[ci][ry][rx] = v;
    }
    __syncthreads();
    int ox = t % HOUT;
    int oyl = (t / HOUT) % OY_PER;
    int cog = t / (HOUT * OY_PER);            // wave-uniform
    const float* wp = w + cog * CO_PER * CIN * 9;
    float acc[CO_PER];
    #pragma unroll
    for (int r = 0; r < CO_PER; r++) acc[r] = bias[cog * CO_PER + r];
    for (int ci = 0; ci < CIN; ci++)
        #pragma unroll
        for (int ky = 0; ky < 3; ky++)
            #pragma unroll
            for (int kx = 0; kx < 3; kx++) {
                float v = tin[ci][2 * oyl + ky][2 * ox + kx];
                #pragma unroll
                for (int r = 0; r < CO_PER; r++)
                    acc[r] = fmaf(v, wp[(r * CIN + ci) * 9 + ky * 3 + kx], acc[r]);
            }
    int oy = oy0 + oyl;
    float s1[CO_PER], s2[CO_PER];
    #pragma unroll
    for (int r = 0; r < CO_PER; r++) {
        float v = fmaxf(acc[r], 0.f);
        out[((b * 24 + cog * CO_PER + r) * HOUT + oy) * HOUT + ox] = v;
        s1[r] = v;
        s2[r] = v * v;
    }
    int lane = t & 63, w_id = t >> 6;
    #pragma unroll
    for (int r = 0; r < CO_PER; r++) {
        float a = s1[r], c2 = s2[r];
        #pragma unroll
        for (int off = 32; off > 0; off >>= 1) {
            a += __shfl_xor(a, off);
            c2 += __shfl_xor(c2, off);
        }
        if (lane == 0) { red[w_id][r * 2] = a; red[w_id][r * 2 + 1] = c2; }
    }
    __syncthreads();
    if (t < 48) {
        int ch = t >> 1, st = t & 1;
        int cg = ch / CO_PER, r = ch % CO_PER;
        float v = 0.f;
        #pragma unroll
        for (int k = 0; k < WPC; k++) v += red[cg * WPC + k][r * 2 + st];
        part_out[blockIdx.x * 48 + t] = v;
    }
}

// ---------------- U/V with inline BN4 finalize+fold ----------------
__global__ __launch_bounds__(256) void uv_kernel(
    const float* __restrict__ x4, const float* __restrict__ p4,
    const float* __restrict__ g4, const float* __restrict__ b4,
    const float* __restrict__ gw1, float* __restrict__ U, float* __restrict__ V)
{
    int b = blockIdx.x >> 2, n0 = (blockIdx.x & 3) * 16;
    __shared__ float o[16][26];
    __shared__ float fred[5][48];
    __shared__ float scf[24], shf[24];
    int t = threadIdx.x;
    if (t < 240) {
        int comp = t % 48, sl = t / 48;
        float a = 0.f;
        for (int p = sl; p < 64; p += 5) a += p4[p * 48 + comp];
        fred[sl][comp] = a;
    }
    __syncthreads();
    if (t < 24) {
        float s1 = 0.f, s2 = 0.f;
        #pragma unroll
        for (int s = 0; s < 5; s++) { s1 += fred[s][2 * t]; s2 += fred[s][2 * t + 1]; }
        float m = s1 * (1.f / 4096.f);
        float var = s2 * (1.f / 4096.f) - m * m;
        float sc = g4[t] * rsqrtf(var + EPS_BN);
        scf[t] = sc;
        shf[t] = fmaf(-m, sc, b4[t]);
    }
    __syncthreads();
    for (int idx = t; idx < 16 * 26; idx += 256) {
        int n = idx / 26, f = idx % 26;
        int ng = n0 + n;
        float val;
        if (f < 24)
            val = fmaf(x4[(b * 24 + f) * 64 + ng], scf[f], shf[f]);
        else if (f == 24) val = (float)(ng >> 3) * 0.125f;
        else              val = (float)(ng & 7) * 0.125f;
        o[n][f] = val;
    }
    __syncthreads();
    float g1u[26], g1v[26];
    #pragma unroll
    for (int f = 0; f < 26; f++) {
        g1u[f] = gw1[f * 256 + t];
        g1v[f] = gw1[(26 + f) * 256 + t];
    }
    for (int n = 0; n < 16; n++) {
        float u = 0.f, v = 0.f;
        #pragma unroll
        for (int f = 0; f < 26; f++) {
            float of = o[n][f];
            u = fmaf(of, g1u[f], u);
            v = fmaf(of, g1v[f], v);
        }
        int ng = n0 + n;
        U[(b * 64 + ng) * 256 + t] = u;
        V[(b * 64 + ng) * 256 + t] = v;
    }
}

// ---------------- fused pair MLP ----------------
// 512 thr, 8 waves, 2 i's (128 rows), 2 blocks/CU, 4 waves/SIMD.
// Layers 1-2 operand-SWAPPED (A=W, B=h): D[c][j]; epilogue writes 4x b64/tile
// (contiguous channel groups). Layer 3 unswapped: colsum in regs.
__global__ __launch_bounds__(512, 4) void pair_kernel(
    const float* __restrict__ U, const float* __restrict__ V,
    const float* __restrict__ wq, const bf16_t* __restrict__ wpack,
    const float* __restrict__ biaspack, const float* __restrict__ gb4,
    float* __restrict__ partial)
{
    __shared__ __align__(16) bf16_t hA[128][264];
    __shared__ float csum[2][256];
    int blk = blockIdx.x;
    int b = blk >> 5;
    int i0 = (blk & 31) * 2;
    int t = threadIdx.x;

    // ---- build h1: thread = (8-col chunk cc, 8-row group jg); b128 writes
    {
        int cc = t & 31, jg = t >> 5;      // jg 0..15 -> rows jg*8..+7
        int c0 = cc * 8;
        int ii = jg >> 3;                  // which i
        const float* Ub = U + (b * 64 + i0 + ii) * 256 + c0;
        const float* Qb = wq + b * 256 + c0;
        fx4 u0 = *(const fx4*)Ub + *(const fx4*)Qb;
        fx4 u1 = *(const fx4*)(Ub + 4) + *(const fx4*)(Qb + 4);
        const float* Vb = V + (b * 64) * 256 + c0;
        int jbase = jg * 8;
        #pragma unroll
        for (int r = 0; r < 8; r++) {
            int j = jbase + r;
            const float* Vr = Vb + (j & 63) * 256;
            fx4 v0 = *(const fx4*)Vr + u0;
            fx4 v1 = *(const fx4*)(Vr + 4) + u1;
            bf16x8 o;
            #pragma unroll
            for (int e = 0; e < 4; e++) {
                o[e]     = (bf16_t)fmaxf(v0[e], 0.f);
                o[e + 4] = (bf16_t)fmaxf(v1[e], 0.f);
            }
            *(bf16x8*)&hA[j][c0] = o;
        }
    }
    __syncthreads();

    int lane = t & 63, wave = t >> 6;
    int l31 = lane & 31, l2 = lane >> 5;
    const floatx16 zero16 = {0.f, 0.f, 0.f, 0.f, 0.f, 0.f, 0.f, 0.f,
                             0.f, 0.f, 0.f, 0.f, 0.f, 0.f, 0.f, 0.f};

    // ---- layers 1-2 (swapped): wave = (cm channels, jn rows)
    int cm = wave & 3, jn = wave >> 2;
    #pragma unroll 1
    for (int lay = 0; lay < 2; lay++) {
        floatx16 acc[2][2];
        #pragma unroll
        for (int mt = 0; mt < 2; mt++)
            #pragma unroll
            for (int nt = 0; nt < 2; nt++) acc[mt][nt] = zero16;

        const bf16_t* W0 = wpack + ((size_t)(lay * 8 + cm * 2) * 16 * 64 + lane) * 8;
        const bf16_t* W1 = W0 + (size_t)16 * 64 * 8;
        bf16x8 Ac[2];
        Ac[0] = *(const bf16x8*)W0;
        Ac[1] = *(const bf16x8*)W1;

        #pragma unroll
        for (int ks = 0; ks < 16; ks++) {
            bf16x8 An[2];
            if (ks < 15) {
                An[0] = *(const bf16x8*)(W0 + (ks + 1) * 64 * 8);
                An[1] = *(const bf16x8*)(W1 + (ks + 1) * 64 * 8);
            }
            bf16x8 b0 = *(const bf16x8*)&hA[jn * 64 + l31][ks * 16 + l2 * 8];
            bf16x8 b1 = *(const bf16x8*)&hA[jn * 64 + 32 + l31][ks * 16 + l2 * 8];
            acc[0][0] = __builtin_amdgcn_mfma_f32_32x32x16_bf16(Ac[0], b0, acc[0][0], 0, 0, 0);
            acc[0][1] = __builtin_amdgcn_mfma_f32_32x32x16_bf16(Ac[0], b1, acc[0][1], 0, 0, 0);
            acc[1][0] = __builtin_amdgcn_mfma_f32_32x32x16_bf16(Ac[1], b0, acc[1][0], 0, 0, 0);
            acc[1][1] = __builtin_amdgcn_mfma_f32_32x32x16_bf16(Ac[1], b1, acc[1][1], 0, 0, 0);
            if (ks < 15) { Ac[0] = An[0]; Ac[1] = An[1]; }
        }
        __syncthreads();
        #pragma unroll
        for (int mt = 0; mt < 2; mt++) {
            const fx4* bp = (const fx4*)(biaspack + lay * 256 + (cm * 2 + mt) * 32 + l2 * 16);
            fx4 bv[4];
            #pragma unroll
            for (int g = 0; g < 4; g++) bv[g] = bp[g];
            int cb = cm * 64 + mt * 32 + 4 * l2;
            #pragma unroll
            for (int nt = 0; nt < 2; nt++) {
                int j = jn * 64 + nt * 32 + l31;
                #pragma unroll
                for (int g = 0; g < 4; g++) {
                    bf16x4 o;
                    #pragma unroll
                    for (int r = 0; r < 4; r++)
                        o[r] = (bf16_t)fmaxf(acc[mt][nt][g * 4 + r] + bv[g][r], 0.f);
                    *(bf16x4*)&hA[j][cb + 8 * g] = o;
                }
            }
        }
        __syncthreads();
    }

    // ---- layer 3 (unswapped): wave = (rm rows, cn cols), colsum in regs
    int rm = wave >> 2, cn = wave & 3;
    float colsum[2] = {0.f, 0.f};
    {
        float bcol[2] = {gb4[cn * 64 + l31], gb4[cn * 64 + 32 + l31]};
        floatx16 acc[2][2];
        #pragma unroll
        for (int mt = 0; mt < 2; mt++)
            #pragma unroll
            for (int nt = 0; nt < 2; nt++) acc[mt][nt] = zero16;
        const bf16_t* B0 = wpack + ((size_t)(16 + cn * 2) * 16 * 64 + lane) * 8;
        const bf16_t* B1 = B0 + (size_t)16 * 64 * 8;
        bf16x8 Bc[2];
        Bc[0] = *(const bf16x8*)B0;
        Bc[1] = *(const bf16x8*)B1;
        #pragma unroll
        for (int ks = 0; ks < 16; ks++) {
            bf16x8 Bn[2];
            if (ks < 15) {
                Bn[0] = *(const bf16x8*)(B0 + (ks + 1) * 64 * 8);
                Bn[1] = *(const bf16x8*)(B1 + (ks + 1) * 64 * 8);
            }
            bf16x8 a0 = *(const bf16x8*)&hA[rm * 64 + l31][ks * 16 + l2 * 8];
            bf16x8 a1 = *(const bf16x8*)&hA[rm * 64 + 32 + l31][ks * 16 + l2 * 8];
            acc[0][0] = __builtin_amdgcn_mfma_f32_32x32x16_bf16(a0, Bc[0], acc[0][0], 0, 0, 0);
            acc[1][0] = __builtin_amdgcn_mfma_f32_32x32x16_bf16(a1, Bc[0], acc[1][0], 0, 0, 0);
            acc[0][1] = __builtin_amdgcn_mfma_f32_32x32x16_bf16(a0, Bc[1], acc[0][1], 0, 0, 0);
            acc[1][1] = __builtin_amdgcn_mfma_f32_32x32x16_bf16(a1, Bc[1], acc[1][1], 0, 0, 0);
            if (ks < 15) { Bc[0] = Bn[0]; Bc[1] = Bn[1]; }
        }
        #pragma unroll
        for (int nt = 0; nt < 2; nt++) {
            float s = 0.f;
            #pragma unroll
            for (int mt = 0; mt < 2; mt++)
                #pragma unroll
                for (int reg = 0; reg < 16; reg++)
                    s += fmaxf(acc[mt][nt][reg] + bcol[nt], 0.0f);
            colsum[nt] += s;
        }
    }
    #pragma unroll
    for (int nt = 0; nt < 2; nt++)
        colsum[nt] += __shfl_xor(colsum[nt], 32);
    if (l2 == 0) {
        #pragma unroll
        for (int nt = 0; nt < 2; nt++)
            csum[rm][cn * 64 + nt * 32 + l31] = colsum[nt];
    }
    __syncthreads();
    if (t < 256)
        partial[blk * 256 + t] = csum[0][t] + csum[1][t];
}

// ---------------- f_phi ----------------
__global__ __launch_bounds__(256) void fphi_kernel(
    const float* __restrict__ partial,
    const float* __restrict__ fw1, const float* __restrict__ fb1,
    const float* __restrict__ fw2, const float* __restrict__ fb2,
    const float* __restrict__ fw3, const float* __restrict__ fb3,
    float* __restrict__ out)
{
    int b = blockIdx.x, t = threadIdx.x;
    __shared__ float g[256], h1[256], h2[256];
    float s = 0.f;
    for (int k = 0; k < 32; k++) s += partial[(b * 32 + k) * 256 + t];
    g[t] = s * (1.0f / 4096.0f);
    __syncthreads();
    float a1 = fb1[t];
    for (int k = 0; k < 256; k++) a1 = fmaf(g[k], fw1[k * 256 + t], a1);
    h1[t] = fmaxf(a1, 0.0f);
    __syncthreads();
    float a2 = fb2[t];
    for (int k = 0; k < 256; k++) a2 = fmaf(h1[k], fw2[k * 256 + t], a2);
    h2[t] = fmaxf(a2, 0.0f);
    __syncthreads();
    if (t < 10) {
        float a3 = fb3[t];
        for (int k = 0; k < 256; k++) a3 = fmaf(h2[k], fw3[k * 10 + t], a3);
        out[b * 10 + t] = a3;
    }
}

extern "C" void kernel_launch(void* const* d_in, const int* in_sizes, int n_in,
                              void* d_out, int out_size, void* d_ws, size_t ws_size,
                              hipStream_t stream)
{
    (void)in_sizes; (void)n_in; (void)out_size; (void)ws_size;
    const float* img = (const float*)d_in[0];
    const float* q   = (const float*)d_in[1];
    const float* cw[4] = {(const float*)d_in[2],  (const float*)d_in[6],
                          (const float*)d_in[10], (const float*)d_in[14]};
    const float* cb[4] = {(const float*)d_in[3],  (const float*)d_in[7],
                          (const float*)d_in[11], (const float*)d_in[15]};
    const float* bg[4] = {(const float*)d_in[4],  (const float*)d_in[8],
                          (const float*)d_in[12], (const float*)d_in[16]};
    const float* bbv[4] = {(const float*)d_in[5],  (const float*)d_in[9],
                           (const float*)d_in[13], (const float*)d_in[17]};
    const float* gw1 = (const float*)d_in[18]; const float* gb1 = (const float*)d_in[19];
    const float* gw2 = (const float*)d_in[20]; const float* gb2 = (const float*)d_in[21];
    const float* gw3 = (const float*)d_in[22]; const float* gb3 = (const float*)d_in[23];
    const float* gw4 = (const float*)d_in[24]; const float* gb4 = (const float*)d_in[25];
    const float* fw1 = (const float*)d_in[26]; const float* fb1 = (const float*)d_in[27];
    const float* fw2 = (const float*)d_in[28]; const float* fb2 = (const float*)d_in[29];
    const float* fw3 = (const float*)d_in[30]; const float* fb3 = (const float*)d_in[31];

    float* ws  = (float*)d_ws;
    float* x1  = ws;                      // 6291456
    float* x2  = x1 + 6291456;            // 1572864
    float* x3  = x2 + 1572864;            // 393216
    float* x4  = x3 + 393216;             // 98304
    float* U   = x4 + 98304;              // 1048576
    float* V   = U + 1048576;             // 1048576
    float* wqv = V + 1048576;             // 16384
    float* part = wqv + 16384;            // 524288
    float* p1  = part + 524288;           // 2048*48
    float* p2  = p1 + 98304;              // 1024*48
    float* p3  = p2 + 49152;              // 256*48
    float* p4  = p3 + 12288;              // 64*48
    float* biaspack = p4 + 3072;          // 512
    bf16_t* wpack = (bf16_t*)(biaspack + 512);  // 3*65536 bf16

    prep_kernel<<<64, 256, 0, stream>>>(q, gw1, gb1, gw2, gw3, gw4, gb2, gb3,
                                        wqv, wpack, biaspack);
    conv_kernel<3, 64, 2, 12, 0><<<2048, 256, 0, stream>>>(
        img, nullptr, 0.f, nullptr, nullptr, cw[0], cb[0], x1, p1);
    conv_kernel<24, 32, 2, 6, 2048><<<1024, 256, 0, stream>>>(
        x1, p1, 1.f / 262144.f, bg[0], bbv[0], cw[1], cb[1], x2, p2);
    conv_kernel<24, 16, 4, 6, 1024><<<256, 256, 0, stream>>>(
        x2, p2, 1.f / 65536.f, bg[1], bbv[1], cw[2], cb[2], x3, p3);
    conv_kernel<24, 8, 8, 6, 256><<<64, 256, 0, stream>>>(
        x3, p3, 1.f / 16384.f, bg[2], bbv[2], cw[3], cb[3], x4, p4);
    uv_kernel<<<256, 256, 0, stream>>>(x4, p4, bg[3], bbv[3], gw1, U, V);
    pair_kernel<<<2048, 512, 0, stream>>>(U, V, wqv, wpack, biaspack, gb4, part);
    fphi_kernel<<<64, 256, 0, stream>>>(part, fw1, fb1, fw2, fb2, fw3, fb3,
                                        (float*)d_out);
}

// Round 8
// 435.671 us; speedup vs baseline: 1.4100x; 1.4100x over previous
//
#include <hip/hip_runtime.h>
#include <hip/hip_bf16.h>

#define EPS_BN 1e-5f

typedef __bf16 bf16_t;
typedef __bf16 bf16x8 __attribute__((ext_vector_type(8)));
typedef __bf16 bf16x4 __attribute__((ext_vector_type(4)));
typedef float fx4 __attribute__((ext_vector_type(4)));
typedef float floatx16 __attribute__((ext_vector_type(16)));

// ---------------- prep: wq + pack W fragments + packed bias ----------------
// wpack layout: (((layer*8 + cg)*16 + kt)*64 + lane)*8 + e
//   col = cg*32 + (lane&31), k = kt*16 + (lane>>5)*8 + e
__global__ __launch_bounds__(256) void prep_kernel(
    const float* __restrict__ q, const float* __restrict__ gw1,
    const float* __restrict__ gb1, const float* __restrict__ g2,
    const float* __restrict__ g3, const float* __restrict__ g4,
    const float* __restrict__ gb2, const float* __restrict__ gb3,
    float* __restrict__ wq, bf16_t* __restrict__ wpack,
    float* __restrict__ biaspack)
{
    int blk = blockIdx.x, t = threadIdx.x;
    {
        float acc = gb1[t];
        #pragma unroll
        for (int d = 0; d < 11; d++)
            acc = fmaf(q[blk * 11 + d], gw1[(52 + d) * 256 + t], acc);
        wq[blk * 256 + t] = acc;
    }
    if (blk == 0) {
        for (int idx = t; idx < 512; idx += 256) {
            int layer = idx >> 8;
            int rem = idx & 255;
            int cg = rem >> 5, l2 = (rem >> 4) & 1, reg = rem & 15;
            int c = cg * 32 + (reg & 3) + 8 * (reg >> 2) + 4 * l2;
            biaspack[idx] = (layer ? gb3 : gb2)[c];
        }
    }
    // full-fragment packing: 24576 frags, 384 per block, b128 stores
    for (int f = blk * 384 + t; f < blk * 384 + 384; f += 256) {
        int lane = f & 63;
        int kt = (f >> 6) & 15;
        int cg = (f >> 10) & 7;
        int layer = f >> 13;
        const float* gw = (layer == 0) ? g2 : ((layer == 1) ? g3 : g4);
        int col = (cg << 5) + (lane & 31);
        int kb = kt * 16 + (lane >> 5) * 8;
        bf16x8 o;
        #pragma unroll
        for (int e = 0; e < 8; e++)
            o[e] = (bf16_t)gw[(kb + e) * 256 + col];
        *(bf16x8*)&wpack[(size_t)f * 8] = o;
    }
}

// ---------------- finalize BN stats: one block per channel ----------------
__global__ __launch_bounds__(256) void fin_kernel(
    const float* __restrict__ part, int P, float inv_n,
    const float* __restrict__ gamma, const float* __restrict__ beta,
    float* __restrict__ scsh)
{
    int c = blockIdx.x;   // 24 channels
    int t = threadIdx.x;
    float s1 = 0.f, s2 = 0.f;
    for (int p = t; p < P; p += 256) {
        s1 += part[p * 48 + 2 * c];
        s2 += part[p * 48 + 2 * c + 1];
    }
    #pragma unroll
    for (int off = 32; off > 0; off >>= 1) {
        s1 += __shfl_xor(s1, off);
        s2 += __shfl_xor(s2, off);
    }
    __shared__ float r1[4], r2[4];
    int lane = t & 63, w = t >> 6;
    if (lane == 0) { r1[w] = s1; r2[w] = s2; }
    __syncthreads();
    if (t == 0) {
        float a1 = r1[0] + r1[1] + r1[2] + r1[3];
        float a2 = r2[0] + r2[1] + r2[2] + r2[3];
        float m = a1 * inv_n;
        float var = a2 * inv_n - m * m;
        float sc = gamma[c] * rsqrtf(var + EPS_BN);
        scsh[c] = sc;
        scsh[24 + c] = fmaf(-m, sc, beta[c]);
    }
}

// ---------------- unified conv ----------------
// PSTAT: 0 = no BN fold (conv1); -1 = fold from precomputed scsh_in;
//        >0 = inline-reduce PSTAT partial rows (only for small PSTAT!)
template<int CIN, int HOUT, int OY_PER, int CO_PER, int PSTAT>
__global__ __launch_bounds__(256) void conv_kernel(
    const float* __restrict__ in, const float* __restrict__ scsh_in,
    const float* __restrict__ part_in, float inv_n,
    const float* __restrict__ gamma, const float* __restrict__ beta,
    const float* __restrict__ w, const float* __restrict__ bias,
    float* __restrict__ out, float* __restrict__ part_out)
{
    const int HIN = 2 * HOUT, ROWS = 2 * OY_PER + 3, RW = 2 * HOUT + 2;
    const int TILES = HOUT / OY_PER;
    const int WPC = (HOUT * OY_PER) / 64;      // waves per channel-group
    int b = blockIdx.x / TILES, tile = blockIdx.x % TILES;
    int oy0 = tile * OY_PER;
    __shared__ float tin[CIN][ROWS][RW];
    __shared__ float scf[24], shf[24];
    __shared__ float fred[5][48];
    __shared__ float red[4][CO_PER * 2];
    int t = threadIdx.x;
    if (PSTAT > 0) {
        if (t < 240) {
            int comp = t % 48, sl = t / 48;
            float a = 0.f;
            for (int p = sl; p < PSTAT; p += 5) a += part_in[p * 48 + comp];
            fred[sl][comp] = a;
        }
        __syncthreads();
        if (t < 24) {
            float s1 = 0.f, s2 = 0.f;
            #pragma unroll
            for (int s = 0; s < 5; s++) { s1 += fred[s][2 * t]; s2 += fred[s][2 * t + 1]; }
            float m = s1 * inv_n;
            float var = s2 * inv_n - m * m;
            float sc = gamma[t] * rsqrtf(var + EPS_BN);
            scf[t] = sc;
            shf[t] = fmaf(-m, sc, beta[t]);
        }
        __syncthreads();
    } else if (PSTAT == -1) {
        if (t < 24) { scf[t] = scsh_in[t]; shf[t] = scsh_in[24 + t]; }
        __syncthreads();
    }
    const int total = CIN * ROWS * RW;
    int iyb = 2 * oy0 - 1;
    #pragma unroll 2
    for (int idx = t; idx < total; idx += 256) {
        int rx = idx % RW;
        int rem = idx / RW;
        int ry = rem % ROWS;
        int ci = rem / ROWS;
        int iy = iyb + ry, ix = rx - 1;
        float v = 0.f;
        if ((unsigned)iy < (unsigned)HIN && (unsigned)ix < (unsigned)HIN) {
            float raw = in[(b * CIN + ci) * HIN * HIN + iy * HIN + ix];
            v = (PSTAT != 0) ? fmaf(raw, scf[ci], shf[ci]) : raw;
        }
        tin[ci][ry][rx] = v;
    }
    __syncthreads();
    int ox = t % HOUT;
    int oyl = (t / HOUT) % OY_PER;
    int cog = t / (HOUT * OY_PER);            // wave-uniform
    const float* wp = w + cog * CO_PER * CIN * 9;
    float acc[CO_PER];
    #pragma unroll
    for (int r = 0; r < CO_PER; r++) acc[r] = bias[cog * CO_PER + r];
    for (int ci = 0; ci < CIN; ci++)
        #pragma unroll
        for (int ky = 0; ky < 3; ky++)
            #pragma unroll
            for (int kx = 0; kx < 3; kx++) {
                float v = tin[ci][2 * oyl + ky][2 * ox + kx];
                #pragma unroll
                for (int r = 0; r < CO_PER; r++)
                    acc[r] = fmaf(v, wp[(r * CIN + ci) * 9 + ky * 3 + kx], acc[r]);
            }
    int oy = oy0 + oyl;
    float s1[CO_PER], s2[CO_PER];
    #pragma unroll
    for (int r = 0; r < CO_PER; r++) {
        float v = fmaxf(acc[r], 0.f);
        out[((b * 24 + cog * CO_PER + r) * HOUT + oy) * HOUT + ox] = v;
        s1[r] = v;
        s2[r] = v * v;
    }
    int lane = t & 63, w_id = t >> 6;
    #pragma unroll
    for (int r = 0; r < CO_PER; r++) {
        float a = s1[r], c2 = s2[r];
        #pragma unroll
        for (int off = 32; off > 0; off >>= 1) {
            a += __shfl_xor(a, off);
            c2 += __shfl_xor(c2, off);
        }
        if (lane == 0) { red[w_id][r * 2] = a; red[w_id][r * 2 + 1] = c2; }
    }
    __syncthreads();
    if (t < 48) {
        int ch = t >> 1, st = t & 1;
        int cg = ch / CO_PER, r = ch % CO_PER;
        float v = 0.f;
        #pragma unroll
        for (int k = 0; k < WPC; k++) v += red[cg * WPC + k][r * 2 + st];
        part_out[blockIdx.x * 48 + t] = v;
    }
}

// ---------------- U/V with inline BN4 finalize (64 rows, cheap) -----------
__global__ __launch_bounds__(256) void uv_kernel(
    const float* __restrict__ x4, const float* __restrict__ p4,
    const float* __restrict__ g4, const float* __restrict__ b4,
    const float* __restrict__ gw1, float* __restrict__ U, float* __restrict__ V)
{
    int b = blockIdx.x >> 2, n0 = (blockIdx.x & 3) * 16;
    __shared__ float o[16][26];
    __shared__ float fred[5][48];
    __shared__ float scf[24], shf[24];
    int t = threadIdx.x;
    if (t < 240) {
        int comp = t % 48, sl = t / 48;
        float a = 0.f;
        for (int p = sl; p < 64; p += 5) a += p4[p * 48 + comp];
        fred[sl][comp] = a;
    }
    __syncthreads();
    if (t < 24) {
        float s1 = 0.f, s2 = 0.f;
        #pragma unroll
        for (int s = 0; s < 5; s++) { s1 += fred[s][2 * t]; s2 += fred[s][2 * t + 1]; }
        float m = s1 * (1.f / 4096.f);
        float var = s2 * (1.f / 4096.f) - m * m;
        float sc = g4[t] * rsqrtf(var + EPS_BN);
        scf[t] = sc;
        shf[t] = fmaf(-m, sc, b4[t]);
    }
    __syncthreads();
    for (int idx = t; idx < 16 * 26; idx += 256) {
        int n = idx / 26, f = idx % 26;
        int ng = n0 + n;
        float val;
        if (f < 24)
            val = fmaf(x4[(b * 24 + f) * 64 + ng], scf[f], shf[f]);
        else if (f == 24) val = (float)(ng >> 3) * 0.125f;
        else              val = (float)(ng & 7) * 0.125f;
        o[n][f] = val;
    }
    __syncthreads();
    float g1u[26], g1v[26];
    #pragma unroll
    for (int f = 0; f < 26; f++) {
        g1u[f] = gw1[f * 256 + t];
        g1v[f] = gw1[(26 + f) * 256 + t];
    }
    for (int n = 0; n < 16; n++) {
        float u = 0.f, v = 0.f;
        #pragma unroll
        for (int f = 0; f < 26; f++) {
            float of = o[n][f];
            u = fmaf(of, g1u[f], u);
            v = fmaf(of, g1v[f], v);
        }
        int ng = n0 + n;
        U[(b * 64 + ng) * 256 + t] = u;
        V[(b * 64 + ng) * 256 + t] = v;
    }
}

// ---------------- fused pair MLP ----------------
// 512 thr, 8 waves, 2 i's (128 rows), 2 blocks/CU, 4 waves/SIMD.
// Layers 1-2 operand-SWAPPED (A=W, B=h): D[c][j]; epilogue writes 4x b64/tile.
// Layer 3 unswapped: colsum in regs.
__global__ __launch_bounds__(512, 4) void pair_kernel(
    const float* __restrict__ U, const float* __restrict__ V,
    const float* __restrict__ wq, const bf16_t* __restrict__ wpack,
    const float* __restrict__ biaspack, const float* __restrict__ gb4,
    float* __restrict__ partial)
{
    __shared__ __align__(16) bf16_t hA[128][264];
    __shared__ float csum[2][256];
    int blk = blockIdx.x;
    int b = blk >> 5;
    int i0 = (blk & 31) * 2;
    int t = threadIdx.x;

    // ---- build h1: thread = (8-col chunk cc, 8-row group jg); b128 writes
    {
        int cc = t & 31, jg = t >> 5;
        int c0 = cc * 8;
        int ii = jg >> 3;
        const float* Ub = U + (b * 64 + i0 + ii) * 256 + c0;
        const float* Qb = wq + b * 256 + c0;
        fx4 u0 = *(const fx4*)Ub + *(const fx4*)Qb;
        fx4 u1 = *(const fx4*)(Ub + 4) + *(const fx4*)(Qb + 4);
        const float* Vb = V + (b * 64) * 256 + c0;
        int jbase = jg * 8;
        #pragma unroll
        for (int r = 0; r < 8; r++) {
            int j = jbase + r;
            const float* Vr = Vb + (j & 63) * 256;
            fx4 v0 = *(const fx4*)Vr + u0;
            fx4 v1 = *(const fx4*)(Vr + 4) + u1;
            bf16x8 o;
            #pragma unroll
            for (int e = 0; e < 4; e++) {
                o[e]     = (bf16_t)fmaxf(v0[e], 0.f);
                o[e + 4] = (bf16_t)fmaxf(v1[e], 0.f);
            }
            *(bf16x8*)&hA[j][c0] = o;
        }
    }
    __syncthreads();

    int lane = t & 63, wave = t >> 6;
    int l31 = lane & 31, l2 = lane >> 5;
    const floatx16 zero16 = {0.f, 0.f, 0.f, 0.f, 0.f, 0.f, 0.f, 0.f,
                             0.f, 0.f, 0.f, 0.f, 0.f, 0.f, 0.f, 0.f};

    // ---- layers 1-2 (swapped): wave = (cm channels, jn rows)
    int cm = wave & 3, jn = wave >> 2;
    #pragma unroll 1
    for (int lay = 0; lay < 2; lay++) {
        floatx16 acc[2][2];
        #pragma unroll
        for (int mt = 0; mt < 2; mt++)
            #pragma unroll
            for (int nt = 0; nt < 2; nt++) acc[mt][nt] = zero16;

        const bf16_t* W0 = wpack + ((size_t)(lay * 8 + cm * 2) * 16 * 64 + lane) * 8;
        const bf16_t* W1 = W0 + (size_t)16 * 64 * 8;
        bf16x8 Ac[2];
        Ac[0] = *(const bf16x8*)W0;
        Ac[1] = *(const bf16x8*)W1;

        #pragma unroll
        for (int ks = 0; ks < 16; ks++) {
            bf16x8 An[2];
            if (ks < 15) {
                An[0] = *(const bf16x8*)(W0 + (ks + 1) * 64 * 8);
                An[1] = *(const bf16x8*)(W1 + (ks + 1) * 64 * 8);
            }
            bf16x8 b0 = *(const bf16x8*)&hA[jn * 64 + l31][ks * 16 + l2 * 8];
            bf16x8 b1 = *(const bf16x8*)&hA[jn * 64 + 32 + l31][ks * 16 + l2 * 8];
            acc[0][0] = __builtin_amdgcn_mfma_f32_32x32x16_bf16(Ac[0], b0, acc[0][0], 0, 0, 0);
            acc[0][1] = __builtin_amdgcn_mfma_f32_32x32x16_bf16(Ac[0], b1, acc[0][1], 0, 0, 0);
            acc[1][0] = __builtin_amdgcn_mfma_f32_32x32x16_bf16(Ac[1], b0, acc[1][0], 0, 0, 0);
            acc[1][1] = __builtin_amdgcn_mfma_f32_32x32x16_bf16(Ac[1], b1, acc[1][1], 0, 0, 0);
            if (ks < 15) { Ac[0] = An[0]; Ac[1] = An[1]; }
        }
        __syncthreads();
        #pragma unroll
        for (int mt = 0; mt < 2; mt++) {
            const fx4* bp = (const fx4*)(biaspack + lay * 256 + (cm * 2 + mt) * 32 + l2 * 16);
            fx4 bv[4];
            #pragma unroll
            for (int g = 0; g < 4; g++) bv[g] = bp[g];
            int cb = cm * 64 + mt * 32 + 4 * l2;
            #pragma unroll
            for (int nt = 0; nt < 2; nt++) {
                int j = jn * 64 + nt * 32 + l31;
                #pragma unroll
                for (int g = 0; g < 4; g++) {
                    bf16x4 o;
                    #pragma unroll
                    for (int r = 0; r < 4; r++)
                        o[r] = (bf16_t)fmaxf(acc[mt][nt][g * 4 + r] + bv[g][r], 0.f);
                    *(bf16x4*)&hA[j][cb + 8 * g] = o;
                }
            }
        }
        __syncthreads();
    }

    // ---- layer 3 (unswapped): wave = (rm rows, cn cols), colsum in regs
    int rm = wave >> 2, cn = wave & 3;
    float colsum[2] = {0.f, 0.f};
    {
        float bcol[2] = {gb4[cn * 64 + l31], gb4[cn * 64 + 32 + l31]};
        floatx16 acc[2][2];
        #pragma unroll
        for (int mt = 0; mt < 2; mt++)
            #pragma unroll
            for (int nt = 0; nt < 2; nt++) acc[mt][nt] = zero16;
        const bf16_t* B0 = wpack + ((size_t)(16 + cn * 2) * 16 * 64 + lane) * 8;
        const bf16_t* B1 = B0 + (size_t)16 * 64 * 8;
        bf16x8 Bc[2];
        Bc[0] = *(const bf16x8*)B0;
        Bc[1] = *(const bf16x8*)B1;
        #pragma unroll
        for (int ks = 0; ks < 16; ks++) {
            bf16x8 Bn[2];
            if (ks < 15) {
                Bn[0] = *(const bf16x8*)(B0 + (ks + 1) * 64 * 8);
                Bn[1] = *(const bf16x8*)(B1 + (ks + 1) * 64 * 8);
            }
            bf16x8 a0 = *(const bf16x8*)&hA[rm * 64 + l31][ks * 16 + l2 * 8];
            bf16x8 a1 = *(const bf16x8*)&hA[rm * 64 + 32 + l31][ks * 16 + l2 * 8];
            acc[0][0] = __builtin_amdgcn_mfma_f32_32x32x16_bf16(a0, Bc[0], acc[0][0], 0, 0, 0);
            acc[1][0] = __builtin_amdgcn_mfma_f32_32x32x16_bf16(a1, Bc[0], acc[1][0], 0, 0, 0);
            acc[0][1] = __builtin_amdgcn_mfma_f32_32x32x16_bf16(a0, Bc[1], acc[0][1], 0, 0, 0);
            acc[1][1] = __builtin_amdgcn_mfma_f32_32x32x16_bf16(a1, Bc[1], acc[1][1], 0, 0, 0);
            if (ks < 15) { Bc[0] = Bn[0]; Bc[1] = Bn[1]; }
        }
        #pragma unroll
        for (int nt = 0; nt < 2; nt++) {
            float s = 0.f;
            #pragma unroll
            for (int mt = 0; mt < 2; mt++)
                #pragma unroll
                for (int reg = 0; reg < 16; reg++)
                    s += fmaxf(acc[mt][nt][reg] + bcol[nt], 0.0f);
            colsum[nt] += s;
        }
    }
    #pragma unroll
    for (int nt = 0; nt < 2; nt++)
        colsum[nt] += __shfl_xor(colsum[nt], 32);
    if (l2 == 0) {
        #pragma unroll
        for (int nt = 0; nt < 2; nt++)
            csum[rm][cn * 64 + nt * 32 + l31] = colsum[nt];
    }
    __syncthreads();
    if (t < 256)
        partial[blk * 256 + t] = csum[0][t] + csum[1][t];
}

// ---------------- f_phi ----------------
__global__ __launch_bounds__(256) void fphi_kernel(
    const float* __restrict__ partial,
    const float* __restrict__ fw1, const float* __restrict__ fb1,
    const float* __restrict__ fw2, const float* __restrict__ fb2,
    const float* __restrict__ fw3, const float* __restrict__ fb3,
    float* __restrict__ out)
{
    int b = blockIdx.x, t = threadIdx.x;
    __shared__ float g[256], h1[256], h2[256];
    float s = 0.f;
    for (int k = 0; k < 32; k++) s += partial[(b * 32 + k) * 256 + t];
    g[t] = s * (1.0f / 4096.0f);
    __syncthreads();
    float a1 = fb1[t];
    for (int k = 0; k < 256; k++) a1 = fmaf(g[k], fw1[k * 256 + t], a1);
    h1[t] = fmaxf(a1, 0.0f);
    __syncthreads();
    float a2 = fb2[t];
    for (int k = 0; k < 256; k++) a2 = fmaf(h1[k], fw2[k * 256 + t], a2);
    h2[t] = fmaxf(a2, 0.0f);
    __syncthreads();
    if (t < 10) {
        float a3 = fb3[t];
        for (int k = 0; k < 256; k++) a3 = fmaf(h2[k], fw3[k * 10 + t], a3);
        out[b * 10 + t] = a3;
    }
}

extern "C" void kernel_launch(void* const* d_in, const int* in_sizes, int n_in,
                              void* d_out, int out_size, void* d_ws, size_t ws_size,
                              hipStream_t stream)
{
    (void)in_sizes; (void)n_in; (void)out_size; (void)ws_size;
    const float* img = (const float*)d_in[0];
    const float* q   = (const float*)d_in[1];
    const float* cw[4] = {(const float*)d_in[2],  (const float*)d_in[6],
                          (const float*)d_in[10], (const float*)d_in[14]};
    const float* cb[4] = {(const float*)d_in[3],  (const float*)d_in[7],
                          (const float*)d_in[11], (const float*)d_in[15]};
    const float* bg[4] = {(const float*)d_in[4],  (const float*)d_in[8],
                          (const float*)d_in[12], (const float*)d_in[16]};
    const float* bbv[4] = {(const float*)d_in[5],  (const float*)d_in[9],
                           (const float*)d_in[13], (const float*)d_in[17]};
    const float* gw1 = (const float*)d_in[18]; const float* gb1 = (const float*)d_in[19];
    const float* gw2 = (const float*)d_in[20]; const float* gb2 = (const float*)d_in[21];
    const float* gw3 = (const float*)d_in[22]; const float* gb3 = (const float*)d_in[23];
    const float* gw4 = (const float*)d_in[24]; const float* gb4 = (const float*)d_in[25];
    const float* fw1 = (const float*)d_in[26]; const float* fb1 = (const float*)d_in[27];
    const float* fw2 = (const float*)d_in[28]; const float* fb2 = (const float*)d_in[29];
    const float* fw3 = (const float*)d_in[30]; const float* fb3 = (const float*)d_in[31];

    float* ws  = (float*)d_ws;
    float* x1  = ws;                      // 6291456
    float* x2  = x1 + 6291456;            // 1572864
    float* x3  = x2 + 1572864;            // 393216
    float* x4  = x3 + 393216;             // 98304
    float* U   = x4 + 98304;              // 1048576
    float* V   = U + 1048576;             // 1048576
    float* wqv = V + 1048576;             // 16384
    float* part = wqv + 16384;            // 524288
    float* p1  = part + 524288;           // 2048*48
    float* p2  = p1 + 98304;              // 1024*48
    float* p3  = p2 + 49152;              // 256*48
    float* p4  = p3 + 12288;              // 64*48
    float* scsh1 = p4 + 3072;             // 48
    float* scsh2 = scsh1 + 48;            // 48
    float* biaspack = scsh2 + 48;         // 512
    bf16_t* wpack = (bf16_t*)(biaspack + 512);  // 3*65536 bf16

    prep_kernel<<<64, 256, 0, stream>>>(q, gw1, gb1, gw2, gw3, gw4, gb2, gb3,
                                        wqv, wpack, biaspack);
    conv_kernel<3, 64, 2, 12, 0><<<2048, 256, 0, stream>>>(
        img, nullptr, nullptr, 0.f, nullptr, nullptr, cw[0], cb[0], x1, p1);
    fin_kernel<<<24, 256, 0, stream>>>(p1, 2048, 1.f / 262144.f, bg[0], bbv[0], scsh1);
    conv_kernel<24, 32, 2, 6, -1><<<1024, 256, 0, stream>>>(
        x1, scsh1, nullptr, 0.f, nullptr, nullptr, cw[1], cb[1], x2, p2);
    fin_kernel<<<24, 256, 0, stream>>>(p2, 1024, 1.f / 65536.f, bg[1], bbv[1], scsh2);
    conv_kernel<24, 16, 4, 6, -1><<<256, 256, 0, stream>>>(
        x2, scsh2, nullptr, 0.f, nullptr, nullptr, cw[2], cb[2], x3, p3);
    conv_kernel<24, 8, 8, 6, 256><<<64, 256, 0, stream>>>(
        x3, nullptr, p3, 1.f / 16384.f, bg[2], bbv[2], cw[3], cb[3], x4, p4);
    uv_kernel<<<256, 256, 0, stream>>>(x4, p4, bg[3], bbv[3], gw1, U, V);
    pair_kernel<<<2048, 512, 0, stream>>>(U, V, wqv, wpack, biaspack, gb4, part);
    fphi_kernel<<<64, 256, 0, stream>>>(part, fw1, fb1, fw2, fb2, fw3, fb3,
                                        (float*)d_out);
}

// Round 9
// 431.804 us; speedup vs baseline: 1.4226x; 1.0090x over previous
//
#include <hip/hip_runtime.h>
#include <hip/hip_bf16.h>

#define EPS_BN 1e-5f

typedef __bf16 bf16_t;
typedef __bf16 bf16x8 __attribute__((ext_vector_type(8)));
typedef __bf16 bf16x4 __attribute__((ext_vector_type(4)));
typedef float fx4 __attribute__((ext_vector_type(4)));
typedef float floatx16 __attribute__((ext_vector_type(16)));

// ---------------- conv1 (blocks 0..2047) + prep (blocks 2048..2111) --------
// wpack layout: (((layer*8 + cg)*16 + kt)*64 + lane)*8 + e
//   col = cg*32 + (lane&31), k = kt*16 + (lane>>5)*8 + e
__global__ __launch_bounds__(256) void c1prep_kernel(
    const float* __restrict__ img, const float* __restrict__ w,
    const float* __restrict__ bias, float* __restrict__ out,
    float* __restrict__ part_out,
    const float* __restrict__ q, const float* __restrict__ gw1,
    const float* __restrict__ gb1, const float* __restrict__ g2,
    const float* __restrict__ g3, const float* __restrict__ g4,
    const float* __restrict__ gb2, const float* __restrict__ gb3,
    float* __restrict__ wq, bf16_t* __restrict__ wpack,
    float* __restrict__ biaspack)
{
    int t = threadIdx.x;
    if (blockIdx.x >= 2048) {
        int blk = blockIdx.x - 2048;
        {   // wq
            float acc = gb1[t];
            #pragma unroll
            for (int d = 0; d < 11; d++)
                acc = fmaf(q[blk * 11 + d], gw1[(52 + d) * 256 + t], acc);
            wq[blk * 256 + t] = acc;
        }
        if (blk == 0) {
            for (int idx = t; idx < 512; idx += 256) {
                int layer = idx >> 8;
                int rem = idx & 255;
                int cg = rem >> 5, l2 = (rem >> 4) & 1, reg = rem & 15;
                int c = cg * 32 + (reg & 3) + 8 * (reg >> 2) + 4 * l2;
                biaspack[idx] = (layer ? gb3 : gb2)[c];
            }
        }
        for (int f = blk * 384 + t; f < blk * 384 + 384; f += 256) {
            int lane = f & 63;
            int kt = (f >> 6) & 15;
            int cg = (f >> 10) & 7;
            int layer = f >> 13;
            const float* gw = (layer == 0) ? g2 : ((layer == 1) ? g3 : g4);
            int col = (cg << 5) + (lane & 31);
            int kb = kt * 16 + (lane >> 5) * 8;
            bf16x8 o;
            #pragma unroll
            for (int e = 0; e < 8; e++)
                o[e] = (bf16_t)gw[(kb + e) * 256 + col];
            *(bf16x8*)&wpack[(size_t)f * 8] = o;
        }
        return;
    }
    // ---- conv1: CIN=3, HOUT=64, OY_PER=2, CO_PER=12
    __shared__ float tin[3][7][130];
    __shared__ float red[4][24];
    int b = blockIdx.x / 32, tile = blockIdx.x % 32;
    int oy0 = tile * 2;
    int iyb = 2 * oy0 - 1;
    #pragma unroll 2
    for (int idx = t; idx < 3 * 7 * 130; idx += 256) {
        int rx = idx % 130;
        int rem = idx / 130;
        int ry = rem % 7;
        int ci = rem / 7;
        int iy = iyb + ry, ix = rx - 1;
        float v = 0.f;
        if ((unsigned)iy < 128u && (unsigned)ix < 128u)
            v = img[(b * 3 + ci) * 16384 + iy * 128 + ix];
        tin[ci][ry][rx] = v;
    }
    __syncthreads();
    int ox = t % 64;
    int oyl = (t / 64) % 2;
    int cog = t / 128;                       // wave-uniform (0..1), 12 co each
    const float* wp = w + cog * 12 * 27;
    float acc[12];
    #pragma unroll
    for (int r = 0; r < 12; r++) acc[r] = bias[cog * 12 + r];
    #pragma unroll
    for (int ci = 0; ci < 3; ci++)
        #pragma unroll
        for (int ky = 0; ky < 3; ky++)
            #pragma unroll
            for (int kx = 0; kx < 3; kx++) {
                float v = tin[ci][2 * oyl + ky][2 * ox + kx];
                #pragma unroll
                for (int r = 0; r < 12; r++)
                    acc[r] = fmaf(v, wp[(r * 3 + ci) * 9 + ky * 3 + kx], acc[r]);
            }
    int oy = oy0 + oyl;
    float s1[12], s2[12];
    #pragma unroll
    for (int r = 0; r < 12; r++) {
        float v = fmaxf(acc[r], 0.f);
        out[((b * 24 + cog * 12 + r) * 64 + oy) * 64 + ox] = v;
        s1[r] = v;
        s2[r] = v * v;
    }
    int lane = t & 63, w_id = t >> 6;
    #pragma unroll
    for (int r = 0; r < 12; r++) {
        float a = s1[r], c2 = s2[r];
        #pragma unroll
        for (int off = 32; off > 0; off >>= 1) {
            a += __shfl_xor(a, off);
            c2 += __shfl_xor(c2, off);
        }
        if (lane == 0) { red[w_id][r * 2] = a; red[w_id][r * 2 + 1] = c2; }
    }
    __syncthreads();
    if (t < 48) {
        int ch = t >> 1, st = t & 1;
        int cg2 = ch / 12, r = ch % 12;
        part_out[blockIdx.x * 48 + t] = red[cg2 * 2][r * 2 + st] + red[cg2 * 2 + 1][r * 2 + st];
    }
}

// ---------------- finalize BN stats: one block per channel ----------------
__global__ __launch_bounds__(256) void fin_kernel(
    const float* __restrict__ part, int P, float inv_n,
    const float* __restrict__ gamma, const float* __restrict__ beta,
    float* __restrict__ scsh)
{
    int c = blockIdx.x;
    int t = threadIdx.x;
    float s1 = 0.f, s2 = 0.f;
    for (int p = t; p < P; p += 256) {
        s1 += part[p * 48 + 2 * c];
        s2 += part[p * 48 + 2 * c + 1];
    }
    #pragma unroll
    for (int off = 32; off > 0; off >>= 1) {
        s1 += __shfl_xor(s1, off);
        s2 += __shfl_xor(s2, off);
    }
    __shared__ float r1[4], r2[4];
    int lane = t & 63, w = t >> 6;
    if (lane == 0) { r1[w] = s1; r2[w] = s2; }
    __syncthreads();
    if (t == 0) {
        float a1 = r1[0] + r1[1] + r1[2] + r1[3];
        float a2 = r2[0] + r2[1] + r2[2] + r2[3];
        float m = a1 * inv_n;
        float var = a2 * inv_n - m * m;
        float sc = gamma[c] * rsqrtf(var + EPS_BN);
        scsh[c] = sc;
        scsh[24 + c] = fmaf(-m, sc, beta[c]);
    }
}

// ---------------- unified conv (conv2..4) ----------------
// PSTAT: -1 = fold from precomputed scsh_in; >0 = inline-reduce PSTAT rows
template<int CIN, int HOUT, int OY_PER, int CO_PER, int PSTAT>
__global__ __launch_bounds__(256) void conv_kernel(
    const float* __restrict__ in, const float* __restrict__ scsh_in,
    const float* __restrict__ part_in, float inv_n,
    const float* __restrict__ gamma, const float* __restrict__ beta,
    const float* __restrict__ w, const float* __restrict__ bias,
    float* __restrict__ out, float* __restrict__ part_out)
{
    const int HIN = 2 * HOUT, ROWS = 2 * OY_PER + 3, RW = 2 * HOUT + 2;
    const int TILES = HOUT / OY_PER;
    const int WPC = (HOUT * OY_PER) / 64;
    int b = blockIdx.x / TILES, tile = blockIdx.x % TILES;
    int oy0 = tile * OY_PER;
    __shared__ float tin[CIN][ROWS][RW];
    __shared__ float scf[24], shf[24];
    __shared__ float fred[5][48];
    __shared__ float red[4][CO_PER * 2];
    int t = threadIdx.x;
    if (PSTAT > 0) {
        if (t < 240) {
            int comp = t % 48, sl = t / 48;
            float a = 0.f;
            for (int p = sl; p < PSTAT; p += 5) a += part_in[p * 48 + comp];
            fred[sl][comp] = a;
        }
        __syncthreads();
        if (t < 24) {
            float s1 = 0.f, s2 = 0.f;
            #pragma unroll
            for (int s = 0; s < 5; s++) { s1 += fred[s][2 * t]; s2 += fred[s][2 * t + 1]; }
            float m = s1 * inv_n;
            float var = s2 * inv_n - m * m;
            float sc = gamma[t] * rsqrtf(var + EPS_BN);
            scf[t] = sc;
            shf[t] = fmaf(-m, sc, beta[t]);
        }
        __syncthreads();
    } else {
        if (t < 24) { scf[t] = scsh_in[t]; shf[t] = scsh_in[24 + t]; }
        __syncthreads();
    }
    const int total = CIN * ROWS * RW;
    int iyb = 2 * oy0 - 1;
    #pragma unroll 2
    for (int idx = t; idx < total; idx += 256) {
        int rx = idx % RW;
        int rem = idx / RW;
        int ry = rem % ROWS;
        int ci = rem / ROWS;
        int iy = iyb + ry, ix = rx - 1;
        float v = 0.f;
        if ((unsigned)iy < (unsigned)HIN && (unsigned)ix < (unsigned)HIN)
            v = fmaf(in[(b * CIN + ci) * HIN * HIN + iy * HIN + ix], scf[ci], shf[ci]);
        tin[ci][ry][rx] = v;
    }
    __syncthreads();
    int ox = t % HOUT;
    int oyl = (t / HOUT) % OY_PER;
    int cog = t / (HOUT * OY_PER);
    const float* wp = w + cog * CO_PER * CIN * 9;
    float acc[CO_PER];
    #pragma unroll
    for (int r = 0; r < CO_PER; r++) acc[r] = bias[cog * CO_PER + r];
    for (int ci = 0; ci < CIN; ci++)
        #pragma unroll
        for (int ky = 0; ky < 3; ky++)
            #pragma unroll
            for (int kx = 0; kx < 3; kx++) {
                float v = tin[ci][2 * oyl + ky][2 * ox + kx];
                #pragma unroll
                for (int r = 0; r < CO_PER; r++)
                    acc[r] = fmaf(v, wp[(r * CIN + ci) * 9 + ky * 3 + kx], acc[r]);
            }
    int oy = oy0 + oyl;
    float s1[CO_PER], s2[CO_PER];
    #pragma unroll
    for (int r = 0; r < CO_PER; r++) {
        float v = fmaxf(acc[r], 0.f);
        out[((b * 24 + cog * CO_PER + r) * HOUT + oy) * HOUT + ox] = v;
        s1[r] = v;
        s2[r] = v * v;
    }
    int lane = t & 63, w_id = t >> 6;
    #pragma unroll
    for (int r = 0; r < CO_PER; r++) {
        float a = s1[r], c2 = s2[r];
        #pragma unroll
        for (int off = 32; off > 0; off >>= 1) {
            a += __shfl_xor(a, off);
            c2 += __shfl_xor(c2, off);
        }
        if (lane == 0) { red[w_id][r * 2] = a; red[w_id][r * 2 + 1] = c2; }
    }
    __syncthreads();
    if (t < 48) {
        int ch = t >> 1, st = t & 1;
        int cg = ch / CO_PER, r = ch % CO_PER;
        float v = 0.f;
        #pragma unroll
        for (int k = 0; k < WPC; k++) v += red[cg * WPC + k][r * 2 + st];
        part_out[blockIdx.x * 48 + t] = v;
    }
}

// ---------------- U/V with inline BN4 finalize ----------------
__global__ __launch_bounds__(256) void uv_kernel(
    const float* __restrict__ x4, const float* __restrict__ p4,
    const float* __restrict__ g4, const float* __restrict__ b4,
    const float* __restrict__ gw1, float* __restrict__ U, float* __restrict__ V)
{
    int b = blockIdx.x >> 2, n0 = (blockIdx.x & 3) * 16;
    __shared__ float o[16][26];
    __shared__ float fred[5][48];
    __shared__ float scf[24], shf[24];
    int t = threadIdx.x;
    if (t < 240) {
        int comp = t % 48, sl = t / 48;
        float a = 0.f;
        for (int p = sl; p < 64; p += 5) a += p4[p * 48 + comp];
        fred[sl][comp] = a;
    }
    __syncthreads();
    if (t < 24) {
        float s1 = 0.f, s2 = 0.f;
        #pragma unroll
        for (int s = 0; s < 5; s++) { s1 += fred[s][2 * t]; s2 += fred[s][2 * t + 1]; }
        float m = s1 * (1.f / 4096.f);
        float var = s2 * (1.f / 4096.f) - m * m;
        float sc = g4[t] * rsqrtf(var + EPS_BN);
        scf[t] = sc;
        shf[t] = fmaf(-m, sc, b4[t]);
    }
    __syncthreads();
    for (int idx = t; idx < 16 * 26; idx += 256) {
        int n = idx / 26, f = idx % 26;
        int ng = n0 + n;
        float val;
        if (f < 24)
            val = fmaf(x4[(b * 24 + f) * 64 + ng], scf[f], shf[f]);
        else if (f == 24) val = (float)(ng >> 3) * 0.125f;
        else              val = (float)(ng & 7) * 0.125f;
        o[n][f] = val;
    }
    __syncthreads();
    float g1u[26], g1v[26];
    #pragma unroll
    for (int f = 0; f < 26; f++) {
        g1u[f] = gw1[f * 256 + t];
        g1v[f] = gw1[(26 + f) * 256 + t];
    }
    for (int n = 0; n < 16; n++) {
        float u = 0.f, v = 0.f;
        #pragma unroll
        for (int f = 0; f < 26; f++) {
            float of = o[n][f];
            u = fmaf(of, g1u[f], u);
            v = fmaf(of, g1v[f], v);
        }
        int ng = n0 + n;
        U[(b * 64 + ng) * 256 + t] = u;
        V[(b * 64 + ng) * 256 + t] = v;
    }
}

// ---------------- fused pair MLP v3 ----------------
// 256 thr (4 waves), 1 i per block (hA 33.8 KB), 3 blocks/CU.
// Layers 1-2 swapped (A=W, B=h), wave=cm (64 cols). Layer 3 unswapped,
// wave=cn (64 cols), colsum in regs, direct store (no cross-wave reduce).
// W prefetched via depth-4 register queue to cover L2 latency.
__global__ __launch_bounds__(256, 3) void pair_kernel(
    const float* __restrict__ U, const float* __restrict__ V,
    const float* __restrict__ wq, const bf16_t* __restrict__ wpack,
    const float* __restrict__ biaspack, const float* __restrict__ gb4,
    float* __restrict__ partial)
{
    __shared__ __align__(16) bf16_t hA[64][264];
    int blk = blockIdx.x;
    int b = blk >> 6;
    int i = blk & 63;
    int t = threadIdx.x;

    // ---- build h1: thread = (8-col chunk cc, 8-row group jg)
    {
        int cc = t & 31, jg = t >> 5;
        int c0 = cc * 8;
        const float* Ub = U + (b * 64 + i) * 256 + c0;
        const float* Qb = wq + b * 256 + c0;
        fx4 u0 = *(const fx4*)Ub + *(const fx4*)Qb;
        fx4 u1 = *(const fx4*)(Ub + 4) + *(const fx4*)(Qb + 4);
        const float* Vb = V + (b * 64) * 256 + c0;
        #pragma unroll
        for (int r = 0; r < 8; r++) {
            int j = jg * 8 + r;
            const float* Vr = Vb + j * 256;
            fx4 v0 = *(const fx4*)Vr + u0;
            fx4 v1 = *(const fx4*)(Vr + 4) + u1;
            bf16x8 o;
            #pragma unroll
            for (int e = 0; e < 4; e++) {
                o[e]     = (bf16_t)fmaxf(v0[e], 0.f);
                o[e + 4] = (bf16_t)fmaxf(v1[e], 0.f);
            }
            *(bf16x8*)&hA[j][c0] = o;
        }
    }
    __syncthreads();

    int lane = t & 63, wave = t >> 6;
    int l31 = lane & 31, l2 = lane >> 5;
    const floatx16 zero16 = {0.f, 0.f, 0.f, 0.f, 0.f, 0.f, 0.f, 0.f,
                             0.f, 0.f, 0.f, 0.f, 0.f, 0.f, 0.f, 0.f};

    // ---- layers 1-2 (swapped): wave cm owns cols cm*64..+63
    int cm = wave;
    #pragma unroll 1
    for (int lay = 0; lay < 2; lay++) {
        floatx16 acc[2][2];
        #pragma unroll
        for (int mt = 0; mt < 2; mt++)
            #pragma unroll
            for (int nt = 0; nt < 2; nt++) acc[mt][nt] = zero16;

        const bf16_t* W0 = wpack + ((size_t)(lay * 8 + cm * 2) * 1024 + lane) * 8;
        const bf16_t* W1 = W0 + 8192;
        bf16x8 Aq[4][2];
        #pragma unroll
        for (int p = 0; p < 4; p++) {
            Aq[p][0] = *(const bf16x8*)(W0 + p * 512);
            Aq[p][1] = *(const bf16x8*)(W1 + p * 512);
        }
        #pragma unroll
        for (int ks = 0; ks < 16; ks++) {
            int slot = ks & 3;
            bf16x8 a0 = Aq[slot][0];
            bf16x8 a1 = Aq[slot][1];
            if (ks < 12) {
                Aq[slot][0] = *(const bf16x8*)(W0 + (ks + 4) * 512);
                Aq[slot][1] = *(const bf16x8*)(W1 + (ks + 4) * 512);
            }
            bf16x8 b0 = *(const bf16x8*)&hA[l31][ks * 16 + l2 * 8];
            bf16x8 b1 = *(const bf16x8*)&hA[32 + l31][ks * 16 + l2 * 8];
            acc[0][0] = __builtin_amdgcn_mfma_f32_32x32x16_bf16(a0, b0, acc[0][0], 0, 0, 0);
            acc[0][1] = __builtin_amdgcn_mfma_f32_32x32x16_bf16(a0, b1, acc[0][1], 0, 0, 0);
            acc[1][0] = __builtin_amdgcn_mfma_f32_32x32x16_bf16(a1, b0, acc[1][0], 0, 0, 0);
            acc[1][1] = __builtin_amdgcn_mfma_f32_32x32x16_bf16(a1, b1, acc[1][1], 0, 0, 0);
        }
        __syncthreads();
        #pragma unroll
        for (int mt = 0; mt < 2; mt++) {
            const fx4* bp = (const fx4*)(biaspack + lay * 256 + (cm * 2 + mt) * 32 + l2 * 16);
            fx4 bv[4];
            #pragma unroll
            for (int g = 0; g < 4; g++) bv[g] = bp[g];
            int cb = cm * 64 + mt * 32 + 4 * l2;
            #pragma unroll
            for (int nt = 0; nt < 2; nt++) {
                int j = nt * 32 + l31;
                #pragma unroll
                for (int g = 0; g < 4; g++) {
                    bf16x4 o;
                    #pragma unroll
                    for (int r = 0; r < 4; r++)
                        o[r] = (bf16_t)fmaxf(acc[mt][nt][g * 4 + r] + bv[g][r], 0.f);
                    *(bf16x4*)&hA[j][cb + 8 * g] = o;
                }
            }
        }
        __syncthreads();
    }

    // ---- layer 3 (unswapped): wave cn owns cols cn*64..+63
    int cn = wave;
    {
        float bcol[2] = {gb4[cn * 64 + l31], gb4[cn * 64 + 32 + l31]};
        floatx16 acc[2][2];
        #pragma unroll
        for (int mt = 0; mt < 2; mt++)
            #pragma unroll
            for (int nt = 0; nt < 2; nt++) acc[mt][nt] = zero16;
        const bf16_t* B0 = wpack + ((size_t)(16 + cn * 2) * 1024 + lane) * 8;
        const bf16_t* B1 = B0 + 8192;
        bf16x8 Bq[4][2];
        #pragma unroll
        for (int p = 0; p < 4; p++) {
            Bq[p][0] = *(const bf16x8*)(B0 + p * 512);
            Bq[p][1] = *(const bf16x8*)(B1 + p * 512);
        }
        #pragma unroll
        for (int ks = 0; ks < 16; ks++) {
            int slot = ks & 3;
            bf16x8 w0 = Bq[slot][0];
            bf16x8 w1 = Bq[slot][1];
            if (ks < 12) {
                Bq[slot][0] = *(const bf16x8*)(B0 + (ks + 4) * 512);
                Bq[slot][1] = *(const bf16x8*)(B1 + (ks + 4) * 512);
            }
            bf16x8 a0 = *(const bf16x8*)&hA[l31][ks * 16 + l2 * 8];
            bf16x8 a1 = *(const bf16x8*)&hA[32 + l31][ks * 16 + l2 * 8];
            acc[0][0] = __builtin_amdgcn_mfma_f32_32x32x16_bf16(a0, w0, acc[0][0], 0, 0, 0);
            acc[1][0] = __builtin_amdgcn_mfma_f32_32x32x16_bf16(a1, w0, acc[1][0], 0, 0, 0);
            acc[0][1] = __builtin_amdgcn_mfma_f32_32x32x16_bf16(a0, w1, acc[0][1], 0, 0, 0);
            acc[1][1] = __builtin_amdgcn_mfma_f32_32x32x16_bf16(a1, w1, acc[1][1], 0, 0, 0);
        }
        float colsum[2];
        #pragma unroll
        for (int nt = 0; nt < 2; nt++) {
            float s = 0.f;
            #pragma unroll
            for (int mt = 0; mt < 2; mt++)
                #pragma unroll
                for (int reg = 0; reg < 16; reg++)
                    s += fmaxf(acc[mt][nt][reg] + bcol[nt], 0.0f);
            colsum[nt] = s;
        }
        #pragma unroll
        for (int nt = 0; nt < 2; nt++)
            colsum[nt] += __shfl_xor(colsum[nt], 32);
        if (l2 == 0) {
            #pragma unroll
            for (int nt = 0; nt < 2; nt++)
                partial[blk * 256 + cn * 64 + nt * 32 + l31] = colsum[nt];
        }
    }
}

// ---------------- f_phi ----------------
__global__ __launch_bounds__(256) void fphi_kernel(
    const float* __restrict__ partial,
    const float* __restrict__ fw1, const float* __restrict__ fb1,
    const float* __restrict__ fw2, const float* __restrict__ fb2,
    const float* __restrict__ fw3, const float* __restrict__ fb3,
    float* __restrict__ out)
{
    int b = blockIdx.x, t = threadIdx.x;
    __shared__ float g[256], h1[256], h2[256];
    float s = 0.f;
    for (int k = 0; k < 64; k++) s += partial[(b * 64 + k) * 256 + t];
    g[t] = s * (1.0f / 4096.0f);
    __syncthreads();
    float a1 = fb1[t];
    for (int k = 0; k < 256; k++) a1 = fmaf(g[k], fw1[k * 256 + t], a1);
    h1[t] = fmaxf(a1, 0.0f);
    __syncthreads();
    float a2 = fb2[t];
    for (int k = 0; k < 256; k++) a2 = fmaf(h1[k], fw2[k * 256 + t], a2);
    h2[t] = fmaxf(a2, 0.0f);
    __syncthreads();
    if (t < 10) {
        float a3 = fb3[t];
        for (int k = 0; k < 256; k++) a3 = fmaf(h2[k], fw3[k * 10 + t], a3);
        out[b * 10 + t] = a3;
    }
}

extern "C" void kernel_launch(void* const* d_in, const int* in_sizes, int n_in,
                              void* d_out, int out_size, void* d_ws, size_t ws_size,
                              hipStream_t stream)
{
    (void)in_sizes; (void)n_in; (void)out_size; (void)ws_size;
    const float* img = (const float*)d_in[0];
    const float* q   = (const float*)d_in[1];
    const float* cw[4] = {(const float*)d_in[2],  (const float*)d_in[6],
                          (const float*)d_in[10], (const float*)d_in[14]};
    const float* cb[4] = {(const float*)d_in[3],  (const float*)d_in[7],
                          (const float*)d_in[11], (const float*)d_in[15]};
    const float* bg[4] = {(const float*)d_in[4],  (const float*)d_in[8],
                          (const float*)d_in[12], (const float*)d_in[16]};
    const float* bbv[4] = {(const float*)d_in[5],  (const float*)d_in[9],
                           (const float*)d_in[13], (const float*)d_in[17]};
    const float* gw1 = (const float*)d_in[18]; const float* gb1 = (const float*)d_in[19];
    const float* gw2 = (const float*)d_in[20]; const float* gb2 = (const float*)d_in[21];
    const float* gw3 = (const float*)d_in[22]; const float* gb3 = (const float*)d_in[23];
    const float* gw4 = (const float*)d_in[24]; const float* gb4 = (const float*)d_in[25];
    const float* fw1 = (const float*)d_in[26]; const float* fb1 = (const float*)d_in[27];
    const float* fw2 = (const float*)d_in[28]; const float* fb2 = (const float*)d_in[29];
    const float* fw3 = (const float*)d_in[30]; const float* fb3 = (const float*)d_in[31];

    float* ws  = (float*)d_ws;
    float* x1  = ws;                      // 6291456
    float* x2  = x1 + 6291456;            // 1572864
    float* x3  = x2 + 1572864;            // 393216
    float* x4  = x3 + 393216;             // 98304
    float* U   = x4 + 98304;              // 1048576
    float* V   = U + 1048576;             // 1048576
    float* wqv = V + 1048576;             // 16384
    float* part = wqv + 16384;            // 4096*256 = 1048576
    float* p1  = part + 1048576;          // 2048*48
    float* p2  = p1 + 98304;              // 1024*48
    float* p3  = p2 + 49152;              // 256*48
    float* p4  = p3 + 12288;              // 64*48
    float* scsh1 = p4 + 3072;             // 48
    float* scsh2 = scsh1 + 48;            // 48
    float* biaspack = scsh2 + 48;         // 512
    bf16_t* wpack = (bf16_t*)(biaspack + 512);  // 3*65536 bf16

    c1prep_kernel<<<2112, 256, 0, stream>>>(
        img, cw[0], cb[0], x1, p1,
        q, gw1, gb1, gw2, gw3, gw4, gb2, gb3, wqv, wpack, biaspack);
    fin_kernel<<<24, 256, 0, stream>>>(p1, 2048, 1.f / 262144.f, bg[0], bbv[0], scsh1);
    conv_kernel<24, 32, 2, 6, -1><<<1024, 256, 0, stream>>>(
        x1, scsh1, nullptr, 0.f, nullptr, nullptr, cw[1], cb[1], x2, p2);
    fin_kernel<<<24, 256, 0, stream>>>(p2, 1024, 1.f / 65536.f, bg[1], bbv[1], scsh2);
    conv_kernel<24, 16, 4, 6, -1><<<256, 256, 0, stream>>>(
        x2, scsh2, nullptr, 0.f, nullptr, nullptr, cw[2], cb[2], x3, p3);
    conv_kernel<24, 8, 8, 6, 256><<<64, 256, 0, stream>>>(
        x3, nullptr, p3, 1.f / 16384.f, bg[2], bbv[2], cw[3], cb[3], x4, p4);
    uv_kernel<<<256, 256, 0, stream>>>(x4, p4, bg[3], bbv[3], gw1, U, V);
    pair_kernel<<<4096, 256, 0, stream>>>(U, V, wqv, wpack, biaspack, gb4, part);
    fphi_kernel<<<64, 256, 0, stream>>>(part, fw1, fb1, fw2, fb2, fw3, fb3,
                                        (float*)d_out);
}